// Round 1
// baseline (149.781 us; speedup 1.0000x reference)
//
#include <hip/hip_runtime.h>
#include <hip/hip_fp16.h>

// B=8, T=S=512, M=N=512, H=128
// score[b,t,s] = (1/sqrt(512)) * sum_h v[h]*tanh(x1[b,t,h]+x2[b,s,h])
// tanh(x) = 1 - 2/(1+e^{2x}) => score = (Sv - 2*sum_h v_h*sigma_h)/SCALE,
//   sigma = 1/(1+e), e = exp2(z), z = 2*log2e*x, x = x1+x2.
// proj stores exp2(z1) factored as (half em, int16 k): exp2(z1)=em*2^k,
// so e = (em_t*em_s)*2^(k_t+k_s)  -> mul+add+ldexp, no exp2 in the hot loop.
// 4-way rcp merge: v1/a1+..+v4/a4 = num/(a1a2a3a4), one rcp per 4 elements.

constexpr float SCALE_IN  = 2.8853900817779268f;   // 2*log2(e)
constexpr float INV_SCALE = 0.04419417382415922f;  // 1/sqrt(512)

// ---------------- Projection GEMM partials (split-k=2) -----------------------
// Grid 512 blocks = 2 k-halves x (2 mats x 128 row-blocks), 512 threads.
// Block: 32 rows x 128 h x 256 k -> 16 waves/CU (was 8) to hide LDS/stage
// latency. Raw fp32 partials go to d_out used as scratch:
// 2 mats * 2 halves * 4096 * 128 floats = 8 MB = exactly out_size.
__global__ __launch_bounds__(512) void proj_partial_kernel(
    const float* __restrict__ q,  const float* __restrict__ w2,
    const float* __restrict__ ky, const float* __restrict__ w1,
    float* __restrict__ part) {
  __shared__ float As[32 * 64];    // [row][k]
  __shared__ float Ws[64 * 128];   // [k][h]

  const int khalf = blockIdx.x >> 8;
  int blk = blockIdx.x & 255;
  const float* A; const float* W; int mat;
  if (blk < 128) { A = q;  W = w2; mat = 0; }
  else           { blk -= 128; A = ky; W = w1; mat = 1; }
  const int rbase = blk * 32;
  const int tid = threadIdx.x;

  const int rq = tid >> 5;          // 0..15 -> rows 2*rq+{0,1}
  const int hq = tid & 31;          // h = 4*hq+{0..3}

  float acc[2][4];
#pragma unroll
  for (int r = 0; r < 2; ++r)
#pragma unroll
    for (int c = 0; c < 4; ++c) acc[r][c] = 0.0f;

  const int k0 = khalf * 256;
  for (int kb = k0; kb < k0 + 256; kb += 64) {
    {
      const int arow = tid >> 4;          // 0..31
      const int kq4  = (tid & 15) * 4;
      *(float4*)(As + arow * 64 + kq4) =
          *(const float4*)(A + (size_t)(rbase + arow) * 512 + kb + kq4);
      const int wrow = tid >> 5;          // 0..15
      const int hq4  = (tid & 31) * 4;
#pragma unroll
      for (int p = 0; p < 4; ++p)
        *(float4*)(Ws + (wrow + 16 * p) * 128 + hq4) =
            *(const float4*)(W + (size_t)(kb + wrow + 16 * p) * 128 + hq4);
    }
    __syncthreads();
#pragma unroll 4
    for (int k4 = 0; k4 < 64; k4 += 4) {
      float a[2][4], w[4][4];
      *(float4*)a[0] = *(const float4*)(As + (2 * rq + 0) * 64 + k4);
      *(float4*)a[1] = *(const float4*)(As + (2 * rq + 1) * 64 + k4);
#pragma unroll
      for (int kk = 0; kk < 4; ++kk)
        *(float4*)w[kk] = *(const float4*)(Ws + (k4 + kk) * 128 + 4 * hq);
#pragma unroll
      for (int kk = 0; kk < 4; ++kk)
#pragma unroll
        for (int r = 0; r < 2; ++r)
#pragma unroll
          for (int c = 0; c < 4; ++c)
            acc[r][c] = fmaf(a[r][kk], w[kk][c], acc[r][c]);
    }
    __syncthreads();
  }

  float* O = part + (size_t)(mat * 2 + khalf) * (4096 * 128);
#pragma unroll
  for (int r = 0; r < 2; ++r)
    *(float4*)(O + (size_t)(rbase + 2 * rq + r) * 128 + 4 * hq) =
        *(float4*)acc[r];
}

// ---------------- Combine k-halves + exp-factor pack -------------------------
// 1024 blocks x 256 threads, 1 float4 per thread. Reads 8MB, writes 4MB packs.
__global__ __launch_bounds__(256) void pack_kernel(
    const float4* __restrict__ part, uint4* __restrict__ o1,
    uint4* __restrict__ o2) {
  const int t = blockIdx.x * 256 + threadIdx.x;   // 0..262143
  const int m = t >> 17;                          // uniform per block
  const int e = t & 131071;                       // row*32 + h4
  const float4 p0 = part[(size_t)(m * 2 + 0) * 131072 + e];
  const float4 p1 = part[(size_t)(m * 2 + 1) * 131072 + e];
  const float x[4] = {p0.x + p1.x, p0.y + p1.y, p0.z + p1.z, p0.w + p1.w};
  unsigned int pk[4];
#pragma unroll
  for (int c = 0; c < 4; ++c) {
    const float z  = x[c] * SCALE_IN;
    const float kf = rintf(z);
    const int   ki = (int)kf;
    const float em = __builtin_amdgcn_exp2f(z - kf);   // in [0.707,1.414]
    pk[c] = ((unsigned int)ki << 16) |
            (unsigned int)__half_as_ushort(__float2half_rn(em));
  }
  (m == 0 ? o1 : o2)[e] = *(const uint4*)pk;
}

// ---------------- Main score kernel -----------------------------------------
// 1024 blocks x 512 threads. Tile 64(t) x 32(s), H staged in two 64-h phases:
// LDS 24KB -> 4 blocks/CU = 32 waves/CU (8/SIMD), was 2 blocks/16 waves.
// Thread: 2 t x 2 s. Same packed math as before.
__global__ __launch_bounds__(512, 8) void score_kernel(
    const unsigned int* __restrict__ x1w, const unsigned int* __restrict__ x2w,
    const float* __restrict__ v, float* __restrict__ out) {
  __shared__ unsigned int x1l[64 * 64];  // [h(64)][t(64)]  16KB
  __shared__ unsigned int x2l[64 * 32];  // [h(64)][s(32)]   8KB

  const int tid   = threadIdx.x;
  const int b     = blockIdx.x >> 7;
  const int tile  = blockIdx.x & 127;
  const int tbase = (tile >> 4) * 64;    // 8 t-tiles
  const int sbase = (tile & 15) * 32;    // 16 s-tiles

  const uint4* x1g = (const uint4*)(x1w) + (size_t)(b * 512 + tbase) * 32;
  const uint4* x2g = (const uint4*)(x2w) + (size_t)(b * 512 + sbase) * 32;

  const int sg = tid & 15;   // s = 2*sg+j
  const int tg = tid >> 4;   // 0..31, t = 2*tg+i

  float racc[2][2] = {{0.0f, 0.0f}, {0.0f, 0.0f}};
  float sv = 0.0f;

  for (int ph = 0; ph < 2; ++ph) {
    // transposed staging: rows distinct across lanes -> <=2-way banks (free)
    {
      const int t1 = tid & 63;
      const int c1 = tid >> 6;            // 0..7
#pragma unroll
      for (int p = 0; p < 2; ++p) {
        const int c4 = c1 + 8 * p;        // 0..15
        const uint4 a = x1g[t1 * 32 + ph * 16 + c4];
        x1l[(4 * c4 + 0) * 64 + t1] = a.x;
        x1l[(4 * c4 + 1) * 64 + t1] = a.y;
        x1l[(4 * c4 + 2) * 64 + t1] = a.z;
        x1l[(4 * c4 + 3) * 64 + t1] = a.w;
      }
      const int s1 = tid & 31;
      const int c2 = tid >> 5;            // 0..15
      const uint4 c = x2g[s1 * 32 + ph * 16 + c2];
      x2l[(4 * c2 + 0) * 32 + s1] = c.x;
      x2l[(4 * c2 + 1) * 32 + s1] = c.y;
      x2l[(4 * c2 + 2) * 32 + s1] = c.z;
      x2l[(4 * c2 + 3) * 32 + s1] = c.w;
    }
    __syncthreads();

    for (int hg = 0; hg < 16; ++hg) {
      const int h0 = hg * 4;
      const float4 vq = *(const float4*)(v + ph * 64 + h0);  // uniform s_load
      sv += (vq.x + vq.y) + (vq.z + vq.w);

      float emt[2][4]; int kt[2][4];
      float ems[2][4]; int ks[2][4];
#pragma unroll
      for (int qq = 0; qq < 4; ++qq) {
        const uint2 tp = *(const uint2*)(x1l + (h0 + qq) * 64 + 2 * tg);
        emt[0][qq] = __half2float(__ushort_as_half((unsigned short)tp.x));
        kt [0][qq] = ((int)tp.x) >> 16;
        emt[1][qq] = __half2float(__ushort_as_half((unsigned short)tp.y));
        kt [1][qq] = ((int)tp.y) >> 16;
        const uint2 sp = *(const uint2*)(x2l + (h0 + qq) * 32 + 2 * sg);
        ems[0][qq] = __half2float(__ushort_as_half((unsigned short)sp.x));
        ks [0][qq] = ((int)sp.x) >> 16;
        ems[1][qq] = __half2float(__ushort_as_half((unsigned short)sp.y));
        ks [1][qq] = ((int)sp.y) >> 16;
      }

#pragma unroll
      for (int i = 0; i < 2; ++i) {
#pragma unroll
        for (int j = 0; j < 2; ++j) {
          float e[4];
#pragma unroll
          for (int qq = 0; qq < 4; ++qq) {
            int kk = kt[i][qq] + ks[j][qq];
            kk = min(kk, 30);                     // den <= 2^124, no inf/NaN
            e[qq] = ldexpf(emt[i][qq] * ems[j][qq], kk);
          }
          const float a0 = e[0] + 1.0f, a1 = e[1] + 1.0f;
          const float a2 = e[2] + 1.0f, a3 = e[3] + 1.0f;
          const float p12 = a0 * a1, p34 = a2 * a3;
          float u1 = vq.x * a1; u1 = fmaf(vq.y, a0, u1);
          float u2 = vq.z * a3; u2 = fmaf(vq.w, a2, u2);
          float num = u1 * p34; num = fmaf(u2, p12, num);
          const float den = p12 * p34;
          racc[i][j] = fmaf(num, __builtin_amdgcn_rcpf(den), racc[i][j]);
        }
      }
    }
    __syncthreads();   // before next phase overwrites LDS
  }

  const float c1v = sv * INV_SCALE;
  const float c2v = -2.0f * INV_SCALE;
#pragma unroll
  for (int i = 0; i < 2; ++i) {
    const int t = tbase + 2 * tg + i;
    float2 o;
    o.x = fmaf(racc[i][0], c2v, c1v);
    o.y = fmaf(racc[i][1], c2v, c1v);
    *(float2*)(out + (size_t)(b * 512 + t) * 512 + sbase + 2 * sg) = o;
  }
}

extern "C" void kernel_launch(void* const* d_in, const int* in_sizes, int n_in,
                              void* d_out, int out_size, void* d_ws, size_t ws_size,
                              hipStream_t stream) {
  const float* query = (const float*)d_in[0];  // (8,512,512)
  const float* keys  = (const float*)d_in[1];  // (8,512,512)
  const float* W1    = (const float*)d_in[2];  // (512,128) pairs with keys
  const float* W2    = (const float*)d_in[3];  // (512,128) pairs with query
  const float* v     = (const float*)d_in[4];  // (128,)
  float* out = (float*)d_out;                  // (8,512,512) fp32

  unsigned int* x1w = (unsigned int*)d_ws;     // 8*512*128 packs (2 MB)
  unsigned int* x2w = x1w + 8 * 512 * 128;     // 2 MB more

  // d_out doubles as split-k scratch (exactly 8 MB); score_kernel fully
  // overwrites it afterwards.
  float* part = (float*)d_out;

  hipLaunchKernelGGL(proj_partial_kernel, dim3(512), dim3(512), 0, stream,
                     query, W2, keys, W1, part);
  hipLaunchKernelGGL(pack_kernel, dim3(1024), dim3(256), 0, stream,
                     (const float4*)part, (uint4*)x1w, (uint4*)x2w);
  hipLaunchKernelGGL(score_kernel, dim3(1024), dim3(512), 0, stream,
                     x1w, x2w, v, out);
}

// Round 2
// 147.590 us; speedup vs baseline: 1.0148x; 1.0148x over previous
//
#include <hip/hip_runtime.h>
#include <hip/hip_fp16.h>

// B=8, T=S=512, M=N=512, H=128
// score[b,t,s] = (1/sqrt(512)) * sum_h v[h]*tanh(x1[b,t,h]+x2[b,s,h])
// tanh(x) = 1 - 2/(1+e^{2x}) => score = (Sv - 2*sum_h v_h*sigma_h)/SCALE,
//   sigma = 1/(1+e), e = exp2(z), z = 2*log2e*x, x = x1+x2.
// proj stores exp2(z1) factored as (half em, int16 k): exp2(z1)=em*2^k,
// so e = (em_t*em_s)*2^(k_t+k_s)  -> mul+add+ldexp, no exp2 in the hot loop.
// 4-way rcp merge: v1/a1+..+v4/a4 = num/(a1a2a3a4), one rcp per 4 elements.

constexpr float SCALE_IN  = 2.8853900817779268f;   // 2*log2(e)
constexpr float INV_SCALE = 0.04419417382415922f;  // 1/sqrt(512)

// ---------------- Projection GEMM partials (split-k=2) -----------------------
// Round-2 retile: proj was LDS-pipe-bound (3 B/FMA; split-k occupancy bump
// changed nothing). Now per-thread 4 rows x 4 h: 8 ds_read_b128 per 64 FMA
// = 2 B/FMA, ~1.0 GB total LDS reads (~20 us pipe floor). A-reads are 2
// distinct addresses per wave (rq = tid>>5 spans 2 values) -> broadcast, free.
// Grid 256 = 2 khalf x 2 mats x 64 row-blocks, 512 threads.
// Block: 64 rows x 128 h x 256 k. LDS 48KB. Partials to d_out scratch (8MB).
__global__ __launch_bounds__(512) void proj_partial_kernel(
    const float* __restrict__ q,  const float* __restrict__ w2,
    const float* __restrict__ ky, const float* __restrict__ w1,
    float* __restrict__ part) {
  __shared__ float As[64 * 64];    // [row][k]  16KB
  __shared__ float Ws[64 * 128];   // [k][h]    32KB

  const int khalf = blockIdx.x >> 7;
  const int rem   = blockIdx.x & 127;
  const int mat   = rem >> 6;
  const int rbase = (rem & 63) * 64;
  const float* A = mat ? ky : q;
  const float* W = mat ? w1 : w2;
  const int tid = threadIdx.x;

  const int rq = tid >> 5;          // 0..15 -> rows 4*rq+{0..3}
  const int hq = tid & 31;          // h = 4*hq+{0..3}

  float acc[4][4];
#pragma unroll
  for (int r = 0; r < 4; ++r)
#pragma unroll
    for (int c = 0; c < 4; ++c) acc[r][c] = 0.0f;

  // staging indices
  const int arow = tid >> 3;          // 0..63
  const int ag   = (tid & 7) * 4;     // word 0..28
  const int wrow = tid >> 5;          // 0..15
  const int wg   = (tid & 31) * 4;    // word 0..124

  const int k0 = khalf * 256;
  for (int kb = k0; kb < k0 + 256; kb += 64) {
    // stage A: 4096 floats, 2 float4/thread
    {
      const float* Ag = A + (size_t)(rbase + arow) * 512 + kb;
      *(float4*)(As + arow * 64 + ag)      = *(const float4*)(Ag + ag);
      *(float4*)(As + arow * 64 + ag + 32) = *(const float4*)(Ag + ag + 32);
      // stage W: 8192 floats, 4 float4/thread
#pragma unroll
      for (int p = 0; p < 4; ++p)
        *(float4*)(Ws + (wrow + 16 * p) * 128 + wg) =
            *(const float4*)(W + (size_t)(kb + wrow + 16 * p) * 128 + wg);
    }
    __syncthreads();
#pragma unroll 2
    for (int k4 = 0; k4 < 64; k4 += 4) {
      float a[4][4], w[4][4];
#pragma unroll
      for (int r = 0; r < 4; ++r)
        *(float4*)a[r] = *(const float4*)(As + (4 * rq + r) * 64 + k4);
#pragma unroll
      for (int kk = 0; kk < 4; ++kk)
        *(float4*)w[kk] = *(const float4*)(Ws + (k4 + kk) * 128 + 4 * hq);
#pragma unroll
      for (int kk = 0; kk < 4; ++kk)
#pragma unroll
        for (int r = 0; r < 4; ++r)
#pragma unroll
          for (int c = 0; c < 4; ++c)
            acc[r][c] = fmaf(a[r][kk], w[kk][c], acc[r][c]);
    }
    __syncthreads();
  }

  float* O = part + (size_t)(mat * 2 + khalf) * (4096 * 128);
#pragma unroll
  for (int r = 0; r < 4; ++r)
    *(float4*)(O + (size_t)(rbase + 4 * rq + r) * 128 + 4 * hq) =
        *(float4*)acc[r];
}

// ---------------- Combine k-halves + exp-factor pack -------------------------
// 1024 blocks x 256 threads, 1 float4 per thread. Reads 8MB, writes 4MB packs.
__global__ __launch_bounds__(256) void pack_kernel(
    const float4* __restrict__ part, uint4* __restrict__ o1,
    uint4* __restrict__ o2) {
  const int t = blockIdx.x * 256 + threadIdx.x;   // 0..262143
  const int m = t >> 17;                          // uniform per block
  const int e = t & 131071;                       // row*32 + h4
  const float4 p0 = part[(size_t)(m * 2 + 0) * 131072 + e];
  const float4 p1 = part[(size_t)(m * 2 + 1) * 131072 + e];
  const float x[4] = {p0.x + p1.x, p0.y + p1.y, p0.z + p1.z, p0.w + p1.w};
  unsigned int pk[4];
#pragma unroll
  for (int c = 0; c < 4; ++c) {
    const float z  = x[c] * SCALE_IN;
    const float kf = rintf(z);
    const int   ki = (int)kf;
    const float em = __builtin_amdgcn_exp2f(z - kf);   // in [0.707,1.414]
    pk[c] = ((unsigned int)ki << 16) |
            (unsigned int)__half_as_ushort(__float2half_rn(em));
  }
  (m == 0 ? o1 : o2)[e] = *(const uint4*)pk;
}

// ---------------- Main score kernel (unchanged from round 1) -----------------
// 1024 blocks x 512 threads. Tile 64(t) x 32(s), H staged in two 64-h phases:
// LDS 24KB -> 4 blocks/CU = 32 waves/CU. Thread: 2 t x 2 s.
// Round-1 evidence: VALU-issue-bound (~81% busy); occupancy and per-thread
// tile size trade off ~exactly, so leave structure alone.
__global__ __launch_bounds__(512, 8) void score_kernel(
    const unsigned int* __restrict__ x1w, const unsigned int* __restrict__ x2w,
    const float* __restrict__ v, float* __restrict__ out) {
  __shared__ unsigned int x1l[64 * 64];  // [h(64)][t(64)]  16KB
  __shared__ unsigned int x2l[64 * 32];  // [h(64)][s(32)]   8KB

  const int tid   = threadIdx.x;
  const int b     = blockIdx.x >> 7;
  const int tile  = blockIdx.x & 127;
  const int tbase = (tile >> 4) * 64;    // 8 t-tiles
  const int sbase = (tile & 15) * 32;    // 16 s-tiles

  const uint4* x1g = (const uint4*)(x1w) + (size_t)(b * 512 + tbase) * 32;
  const uint4* x2g = (const uint4*)(x2w) + (size_t)(b * 512 + sbase) * 32;

  const int sg = tid & 15;   // s = 2*sg+j
  const int tg = tid >> 4;   // 0..31, t = 2*tg+i

  float racc[2][2] = {{0.0f, 0.0f}, {0.0f, 0.0f}};
  float sv = 0.0f;

  for (int ph = 0; ph < 2; ++ph) {
    // transposed staging: rows distinct across lanes -> <=2-way banks (free)
    {
      const int t1 = tid & 63;
      const int c1 = tid >> 6;            // 0..7
#pragma unroll
      for (int p = 0; p < 2; ++p) {
        const int c4 = c1 + 8 * p;        // 0..15
        const uint4 a = x1g[t1 * 32 + ph * 16 + c4];
        x1l[(4 * c4 + 0) * 64 + t1] = a.x;
        x1l[(4 * c4 + 1) * 64 + t1] = a.y;
        x1l[(4 * c4 + 2) * 64 + t1] = a.z;
        x1l[(4 * c4 + 3) * 64 + t1] = a.w;
      }
      const int s1 = tid & 31;
      const int c2 = tid >> 5;            // 0..15
      const uint4 c = x2g[s1 * 32 + ph * 16 + c2];
      x2l[(4 * c2 + 0) * 32 + s1] = c.x;
      x2l[(4 * c2 + 1) * 32 + s1] = c.y;
      x2l[(4 * c2 + 2) * 32 + s1] = c.z;
      x2l[(4 * c2 + 3) * 32 + s1] = c.w;
    }
    __syncthreads();

    for (int hg = 0; hg < 16; ++hg) {
      const int h0 = hg * 4;
      const float4 vq = *(const float4*)(v + ph * 64 + h0);  // uniform s_load
      sv += (vq.x + vq.y) + (vq.z + vq.w);

      float emt[2][4]; int kt[2][4];
      float ems[2][4]; int ks[2][4];
#pragma unroll
      for (int qq = 0; qq < 4; ++qq) {
        const uint2 tp = *(const uint2*)(x1l + (h0 + qq) * 64 + 2 * tg);
        emt[0][qq] = __half2float(__ushort_as_half((unsigned short)tp.x));
        kt [0][qq] = ((int)tp.x) >> 16;
        emt[1][qq] = __half2float(__ushort_as_half((unsigned short)tp.y));
        kt [1][qq] = ((int)tp.y) >> 16;
        const uint2 sp = *(const uint2*)(x2l + (h0 + qq) * 32 + 2 * sg);
        ems[0][qq] = __half2float(__ushort_as_half((unsigned short)sp.x));
        ks [0][qq] = ((int)sp.x) >> 16;
        ems[1][qq] = __half2float(__ushort_as_half((unsigned short)sp.y));
        ks [1][qq] = ((int)sp.y) >> 16;
      }

#pragma unroll
      for (int i = 0; i < 2; ++i) {
#pragma unroll
        for (int j = 0; j < 2; ++j) {
          float e[4];
#pragma unroll
          for (int qq = 0; qq < 4; ++qq) {
            int kk = kt[i][qq] + ks[j][qq];
            kk = min(kk, 30);                     // den <= 2^124, no inf/NaN
            e[qq] = ldexpf(emt[i][qq] * ems[j][qq], kk);
          }
          const float a0 = e[0] + 1.0f, a1 = e[1] + 1.0f;
          const float a2 = e[2] + 1.0f, a3 = e[3] + 1.0f;
          const float p12 = a0 * a1, p34 = a2 * a3;
          float u1 = vq.x * a1; u1 = fmaf(vq.y, a0, u1);
          float u2 = vq.z * a3; u2 = fmaf(vq.w, a2, u2);
          float num = u1 * p34; num = fmaf(u2, p12, num);
          const float den = p12 * p34;
          racc[i][j] = fmaf(num, __builtin_amdgcn_rcpf(den), racc[i][j]);
        }
      }
    }
    __syncthreads();   // before next phase overwrites LDS
  }

  const float c1v = sv * INV_SCALE;
  const float c2v = -2.0f * INV_SCALE;
#pragma unroll
  for (int i = 0; i < 2; ++i) {
    const int t = tbase + 2 * tg + i;
    float2 o;
    o.x = fmaf(racc[i][0], c2v, c1v);
    o.y = fmaf(racc[i][1], c2v, c1v);
    *(float2*)(out + (size_t)(b * 512 + t) * 512 + sbase + 2 * sg) = o;
  }
}

extern "C" void kernel_launch(void* const* d_in, const int* in_sizes, int n_in,
                              void* d_out, int out_size, void* d_ws, size_t ws_size,
                              hipStream_t stream) {
  const float* query = (const float*)d_in[0];  // (8,512,512)
  const float* keys  = (const float*)d_in[1];  // (8,512,512)
  const float* W1    = (const float*)d_in[2];  // (512,128) pairs with keys
  const float* W2    = (const float*)d_in[3];  // (512,128) pairs with query
  const float* v     = (const float*)d_in[4];  // (128,)
  float* out = (float*)d_out;                  // (8,512,512) fp32

  unsigned int* x1w = (unsigned int*)d_ws;     // 8*512*128 packs (2 MB)
  unsigned int* x2w = x1w + 8 * 512 * 128;     // 2 MB more

  // d_out doubles as split-k scratch (exactly 8 MB); score_kernel fully
  // overwrites it afterwards.
  float* part = (float*)d_out;

  hipLaunchKernelGGL(proj_partial_kernel, dim3(256), dim3(512), 0, stream,
                     query, W2, keys, W1, part);
  hipLaunchKernelGGL(pack_kernel, dim3(1024), dim3(256), 0, stream,
                     (const float4*)part, (uint4*)x1w, (uint4*)x2w);
  hipLaunchKernelGGL(score_kernel, dim3(1024), dim3(512), 0, stream,
                     x1w, x2w, v, out);
}

// Round 3
// 145.342 us; speedup vs baseline: 1.0305x; 1.0155x over previous
//
#include <hip/hip_runtime.h>
#include <hip/hip_fp16.h>

// B=8, T=S=512, M=N=512, H=128
// score[b,t,s] = (1/sqrt(512)) * sum_h v[h]*tanh(x1[b,t,h]+x2[b,s,h])
// tanh(x) = 1 - 2/(1+e^{2x}) => score = (Sv - 2*sum_h v_h*sigma_h)/SCALE,
//   sigma = 1/(1+e), e = exp2(z1+z2), z_i = 2*log2(e)*x_i  (z stored f32).
// Round-3: direct v_exp_f32 per element (4 instr: add,min,exp2,add1) replaces
// the packed (em f16, k i16) pipeline (~7 instr w/ unpack+cvt+ldexp). exp2 is
// 1/4-rate but instruction count (what compiler fat scales with) drops 35%.
// 4-way rcp merge: v1/a1+..+v4/a4 = num/(a1a2a3a4), one rcp per 4 elements.

constexpr float SCALE_IN  = 2.8853900817779268f;   // 2*log2(e)
constexpr float INV_SCALE = 0.04419417382415922f;  // 1/sqrt(512)

// ---------------- Projection GEMM partials (split-k=2) -----------------------
// 64 rows x 128 h x 256 k per block; per-thread 4r x 4h (2 B/FMA LDS).
// Grid 256 = 2 khalf x 2 mats x 64 row-blocks, 512 threads. LDS 48KB.
// Raw fp32 partials to d_out scratch (2*2*4096*128*4 = 8 MB = out_size).
__global__ __launch_bounds__(512) void proj_partial_kernel(
    const float* __restrict__ q,  const float* __restrict__ w2,
    const float* __restrict__ ky, const float* __restrict__ w1,
    float* __restrict__ part) {
  __shared__ float As[64 * 64];    // [row][k]  16KB
  __shared__ float Ws[64 * 128];   // [k][h]    32KB

  const int khalf = blockIdx.x >> 7;
  const int rem   = blockIdx.x & 127;
  const int mat   = rem >> 6;
  const int rbase = (rem & 63) * 64;
  const float* A = mat ? ky : q;
  const float* W = mat ? w1 : w2;
  const int tid = threadIdx.x;

  const int rq = tid >> 5;          // 0..15 -> rows 4*rq+{0..3}
  const int hq = tid & 31;          // h = 4*hq+{0..3}

  float acc[4][4];
#pragma unroll
  for (int r = 0; r < 4; ++r)
#pragma unroll
    for (int c = 0; c < 4; ++c) acc[r][c] = 0.0f;

  const int arow = tid >> 3;          // 0..63
  const int ag   = (tid & 7) * 4;     // word 0..28
  const int wrow = tid >> 5;          // 0..15
  const int wg   = (tid & 31) * 4;    // word 0..124

  const int k0 = khalf * 256;
  for (int kb = k0; kb < k0 + 256; kb += 64) {
    {
      const float* Ag = A + (size_t)(rbase + arow) * 512 + kb;
      *(float4*)(As + arow * 64 + ag)      = *(const float4*)(Ag + ag);
      *(float4*)(As + arow * 64 + ag + 32) = *(const float4*)(Ag + ag + 32);
#pragma unroll
      for (int p = 0; p < 4; ++p)
        *(float4*)(Ws + (wrow + 16 * p) * 128 + wg) =
            *(const float4*)(W + (size_t)(kb + wrow + 16 * p) * 128 + wg);
    }
    __syncthreads();
#pragma unroll 2
    for (int k4 = 0; k4 < 64; k4 += 4) {
      float a[4][4], w[4][4];
#pragma unroll
      for (int r = 0; r < 4; ++r)
        *(float4*)a[r] = *(const float4*)(As + (4 * rq + r) * 64 + k4);
#pragma unroll
      for (int kk = 0; kk < 4; ++kk)
        *(float4*)w[kk] = *(const float4*)(Ws + (k4 + kk) * 128 + 4 * hq);
#pragma unroll
      for (int kk = 0; kk < 4; ++kk)
#pragma unroll
        for (int r = 0; r < 4; ++r)
#pragma unroll
          for (int c = 0; c < 4; ++c)
            acc[r][c] = fmaf(a[r][kk], w[kk][c], acc[r][c]);
    }
    __syncthreads();
  }

  float* O = part + (size_t)(mat * 2 + khalf) * (4096 * 128);
#pragma unroll
  for (int r = 0; r < 4; ++r)
    *(float4*)(O + (size_t)(rbase + 4 * rq + r) * 128 + 4 * hq) =
        *(float4*)acc[r];
}

// ---------------- Combine k-halves -> z planes (f32) -------------------------
// z = (p0+p1) * 2log2e. Pure elementwise now (no pack). 1024 x 256, float4/thr.
__global__ __launch_bounds__(256) void combine_kernel(
    const float4* __restrict__ part, float4* __restrict__ z1,
    float4* __restrict__ z2) {
  const int t = blockIdx.x * 256 + threadIdx.x;   // 0..262143
  const int m = t >> 17;                          // uniform per block
  const int e = t & 131071;                       // row*32 + h4
  const float4 p0 = part[(size_t)(m * 2 + 0) * 131072 + e];
  const float4 p1 = part[(size_t)(m * 2 + 1) * 131072 + e];
  float4 z;
  z.x = (p0.x + p1.x) * SCALE_IN;
  z.y = (p0.y + p1.y) * SCALE_IN;
  z.z = (p0.z + p1.z) * SCALE_IN;
  z.w = (p0.w + p1.w) * SCALE_IN;
  (m == 0 ? z1 : z2)[e] = z;
}

// ---------------- Main score kernel -----------------------------------------
// 512 blocks x 512 threads. Tile 64(t) x 64(s), H in two 64-h phases.
// LDS 32KB ([64h][64t] + [64h][64s] f32). Thread: 2 t x 4 s.
// Inner per element: v_add + v_min + v_exp_f32 + v_add, then 4-way rcp merge.
__global__ __launch_bounds__(512, 4) void score_kernel(
    const float* __restrict__ x1z, const float* __restrict__ x2z,
    const float* __restrict__ v, float* __restrict__ out) {
  __shared__ float x1l[64 * 64];  // [h(64)][t(64)] 16KB
  __shared__ float x2l[64 * 64];  // [h(64)][s(64)] 16KB

  const int tid   = threadIdx.x;
  const int b     = blockIdx.x >> 6;
  const int tile  = blockIdx.x & 63;
  const int tbase = (tile >> 3) * 64;    // 8 t-tiles
  const int sbase = (tile & 7) * 64;     // 8 s-tiles

  const float* x1g = x1z + (size_t)(b * 512 + tbase) * 128;
  const float* x2g = x2z + (size_t)(b * 512 + sbase) * 128;

  const int sg = tid & 15;   // s = 4*sg+j (coalesced float4 stores)
  const int tg = tid >> 4;   // 0..31, t = 2*tg+i

  float racc[2][4];
#pragma unroll
  for (int i = 0; i < 2; ++i)
#pragma unroll
    for (int j = 0; j < 4; ++j) racc[i][j] = 0.0f;
  float sv = 0.0f;

  for (int ph = 0; ph < 2; ++ph) {
    // transposed staging: [row][h] global -> [h][row] LDS.
    // writes: 64 lanes hit 256B contiguous -> 2-way banks (free).
    {
      const int r1 = tid & 63;            // row within tile
      const int c0 = tid >> 6;            // 0..7
#pragma unroll
      for (int p = 0; p < 2; ++p) {
        const int c = c0 + 8 * p;         // 0..15 -> h = 4c..4c+3
        const float4 a =
            *(const float4*)(x1g + (size_t)r1 * 128 + ph * 64 + 4 * c);
        x1l[(4 * c + 0) * 64 + r1] = a.x;
        x1l[(4 * c + 1) * 64 + r1] = a.y;
        x1l[(4 * c + 2) * 64 + r1] = a.z;
        x1l[(4 * c + 3) * 64 + r1] = a.w;
        const float4 s =
            *(const float4*)(x2g + (size_t)r1 * 128 + ph * 64 + 4 * c);
        x2l[(4 * c + 0) * 64 + r1] = s.x;
        x2l[(4 * c + 1) * 64 + r1] = s.y;
        x2l[(4 * c + 2) * 64 + r1] = s.z;
        x2l[(4 * c + 3) * 64 + r1] = s.w;
      }
    }
    __syncthreads();

    for (int hg = 0; hg < 16; ++hg) {
      const int h0 = hg * 4;
      const float4 vq = *(const float4*)(v + ph * 64 + h0);  // uniform s_load
      sv += (vq.x + vq.y) + (vq.z + vq.w);

      float zt[2][4];   // [i][qq]
      float zs[4][4];   // [j][qq]
#pragma unroll
      for (int qq = 0; qq < 4; ++qq) {
        const float2 tp = *(const float2*)(x1l + (h0 + qq) * 64 + 2 * tg);
        zt[0][qq] = tp.x;
        zt[1][qq] = tp.y;
        const float4 sp = *(const float4*)(x2l + (h0 + qq) * 64 + 4 * sg);
        zs[0][qq] = sp.x;
        zs[1][qq] = sp.y;
        zs[2][qq] = sp.z;
        zs[3][qq] = sp.w;
      }

#pragma unroll
      for (int i = 0; i < 2; ++i) {
#pragma unroll
        for (int j = 0; j < 4; ++j) {
          float e[4];
#pragma unroll
          for (int qq = 0; qq < 4; ++qq) {
            const float z = fminf(zt[i][qq] + zs[j][qq], 30.0f);
            e[qq] = __builtin_amdgcn_exp2f(z);   // e <= 2^30; underflow -> 0
          }
          const float a0 = e[0] + 1.0f, a1 = e[1] + 1.0f;
          const float a2 = e[2] + 1.0f, a3 = e[3] + 1.0f;
          const float p12 = a0 * a1, p34 = a2 * a3;  // den <= 2^120, no inf
          float u1 = vq.x * a1; u1 = fmaf(vq.y, a0, u1);
          float u2 = vq.z * a3; u2 = fmaf(vq.w, a2, u2);
          float num = u1 * p34; num = fmaf(u2, p12, num);
          const float den = p12 * p34;
          racc[i][j] = fmaf(num, __builtin_amdgcn_rcpf(den), racc[i][j]);
        }
      }
    }
    __syncthreads();   // before next phase overwrites LDS
  }

  const float c1v = sv * INV_SCALE;
  const float c2v = -2.0f * INV_SCALE;
#pragma unroll
  for (int i = 0; i < 2; ++i) {
    const int t = tbase + 2 * tg + i;
    float4 o;
    o.x = fmaf(racc[i][0], c2v, c1v);
    o.y = fmaf(racc[i][1], c2v, c1v);
    o.z = fmaf(racc[i][2], c2v, c1v);
    o.w = fmaf(racc[i][3], c2v, c1v);
    *(float4*)(out + (size_t)(b * 512 + t) * 512 + sbase + 4 * sg) = o;
  }
}

extern "C" void kernel_launch(void* const* d_in, const int* in_sizes, int n_in,
                              void* d_out, int out_size, void* d_ws, size_t ws_size,
                              hipStream_t stream) {
  const float* query = (const float*)d_in[0];  // (8,512,512)
  const float* keys  = (const float*)d_in[1];  // (8,512,512)
  const float* W1    = (const float*)d_in[2];  // (512,128) pairs with keys
  const float* W2    = (const float*)d_in[3];  // (512,128) pairs with query
  const float* v     = (const float*)d_in[4];  // (128,)
  float* out = (float*)d_out;                  // (8,512,512) fp32

  float* x1zp = (float*)d_ws;                  // 8*512*128 f32 (2 MB)
  float* x2zp = x1zp + 8 * 512 * 128;          // 2 MB more

  // d_out doubles as split-k scratch (exactly 8 MB); score_kernel fully
  // overwrites it afterwards.
  float* part = (float*)d_out;

  hipLaunchKernelGGL(proj_partial_kernel, dim3(256), dim3(512), 0, stream,
                     query, W2, keys, W1, part);
  hipLaunchKernelGGL(combine_kernel, dim3(1024), dim3(256), 0, stream,
                     (const float4*)part, (float4*)x1zp, (float4*)x2zp);
  hipLaunchKernelGGL(score_kernel, dim3(512), dim3(512), 0, stream,
                     x1zp, x2zp, v, out);
}